// Round 3
// baseline (16618.694 us; speedup 1.0000x reference)
//
#include <hip/hip_runtime.h>
#include <hip/hip_cooperative_groups.h>

namespace cg = cooperative_groups;

#define M_ROWS 2048
#define N_COLS 4096
#define RHO_C 1.0f
#define STEP_C 5e-05f
#define MAX_ITERS_C 100
#define INNER_C 20

// Agent-scope relaxed atomics (sc1 path: coherent at the Infinity Cache).
__device__ __forceinline__ unsigned long long ald64(const unsigned long long* p) {
    return __hip_atomic_load(p, __ATOMIC_RELAXED, __HIP_MEMORY_SCOPE_AGENT);
}
__device__ __forceinline__ void ast64(unsigned long long* p, unsigned long long v) {
    __hip_atomic_store(p, v, __ATOMIC_RELAXED, __HIP_MEMORY_SCOPE_AGENT);
}
__device__ __forceinline__ unsigned aldu(const unsigned* p) {
    return __hip_atomic_load(p, __ATOMIC_RELAXED, __HIP_MEMORY_SCOPE_AGENT);
}
__device__ __forceinline__ void astu(unsigned* p, unsigned v) {
    __hip_atomic_store(p, v, __ATOMIC_RELAXED, __HIP_MEMORY_SCOPE_AGENT);
}
__device__ __forceinline__ float2 u2f(unsigned long long v) {
    union { unsigned long long u; float2 f; } c; c.u = v; return c.f;
}
__device__ __forceinline__ unsigned long long f2u(float a, float b) {
    union { float2 f; unsigned long long u; } c; c.f = make_float2(a, b); return c.u;
}

// Consumer side of the x exchange for round TAG:
//  - poll ONLY the producing block's flag (4 B; wave-coalesced: 64 lanes
//    cover 16 flags = one 64-B line per wave per sweep)
//  - then load this thread's 16 B of the producer's 64-B line ONCE.
// Release/acquire: producer drained vmcnt(0) before the flag store, and all
// accesses are agent-scope (MALL point of coherence), so flag-visible =>
// data-visible. Compiler barrier stops hoisting of the data loads.
#define STAGE_X(TAG)                                                         \
    {                                                                        \
        const int pb = tid >> 2;                                             \
        if (pb != blk) {                                                     \
            while (aldu(&flagX[pb]) < (unsigned)(TAG))                       \
                __builtin_amdgcn_s_sleep(1);                                 \
            asm volatile("" ::: "memory");                                   \
            const unsigned long long* src =                                  \
                xL + ((((unsigned)(TAG)) & 1u) ? 2048u : 0u)                 \
                   + ((unsigned)tid << 1);                                   \
            float2 a = u2f(ald64(src)), b = u2f(ald64(src + 1));             \
            xs4[tid] = make_float4(a.x, a.y, b.x, b.y);                      \
        }                                                                    \
    }                                                                        \
    __syncthreads();

// 256 blocks (1/CU) x 1024 threads (16 waves), persistent cooperative kernel.
// Gram form: g = c + rho*(M x - A^T rt), M = A^T A held ENTIRELY in registers.
// Cross-block exchange: per-block 64-B data line + per-block monotone u32
// flag (release via s_waitcnt vmcnt(0)). Read-once data, poll-only-flags.
__global__ __launch_bounds__(1024) void admm_flag(
    const float* __restrict__ A, const float* __restrict__ bvec,
    const float* __restrict__ cvec, float* __restrict__ out,
    unsigned long long* __restrict__ xL,   // 2 slots x 256 blocks x 8 u64
    unsigned long long* __restrict__ rtL,  // 256 blocks x 4 u64
    unsigned* __restrict__ flagX,          // 256 monotone tags (x rounds)
    unsigned* __restrict__ flagR)          // 256 monotone tags (rt/outer)
{
    cg::grid_group grid = cg::this_grid();
    const int tid  = threadIdx.x;
    const int blk  = blockIdx.x;
    const int lane = tid & 63;
    const int wave = tid >> 6;
    const int cgp  = wave >> 2;   // col-group: cols [1024*cgp, +1024)
    const int rq   = wave & 3;    // row-quad : rows 16*blk + 4*rq .. +4

    __shared__ float  abuf[4 * N_COLS];  // 64 KB staging (A rows / rt)
    __shared__ float4 xs4[1024];         // 16 KB staged x
    __shared__ float  red[4][16];        // per-colgroup row partials
    __shared__ float4 gred[64];          // w-phase reduce scratch
    __shared__ float  wl[16], cw[16];
    __shared__ float  sv[8], uv[8], bv[8], tpart[16];

    float* xs = reinterpret_cast<float*>(xs4);
    const float4* A4 = reinterpret_cast<const float4*>(A);
    float4* abuf4 = reinterpret_cast<float4*>(abuf);

    // ---- init: each block rewrites its OWN lines+flags (re-poison safe) ----
    if (tid < 16) {
        cw[tid] = cvec[blk * 16 + tid];
        xs[blk * 16 + tid] = 0.0f;                 // own x@0 in LDS
    }
    if (tid < 8) {
        sv[tid] = 0.0f; uv[tid] = 0.0f;
        bv[tid] = bvec[blk * 8 + tid];
        ast64(xL + blk * 8 + tid, 0ull);           // slot0 = x@0 = 0
    }
    if (tid < 4)
        ast64(rtL + blk * 4 + tid,
              f2u(bvec[blk * 8 + 2 * tid], bvec[blk * 8 + 2 * tid + 1]));
    if (tid == 0) { astu(&flagX[blk], 0u); astu(&flagR[blk], 0u); }

    // ---- precompute register-resident M fragment ----
    float accM[4][16];
    #pragma unroll
    for (int r = 0; r < 4; ++r)
        #pragma unroll
        for (int k = 0; k < 16; ++k) accM[r][k] = 0.0f;

    for (int i0 = 0; i0 < M_ROWS; i0 += 4) {
        #pragma unroll
        for (int ii = 0; ii < 4; ++ii)
            abuf4[ii * 1024 + tid] = A4[(size_t)(i0 + ii) * 1024 + tid];
        __syncthreads();
        #pragma unroll
        for (int ii = 0; ii < 4; ++ii) {
            const float*  row  = abuf + ii * N_COLS;
            const float4* row4 = abuf4 + ii * 1024;
            float4 av[4];
            #pragma unroll
            for (int q = 0; q < 4; ++q)
                av[q] = row4[256 * cgp + 64 * q + lane];
            float cb[4];
            #pragma unroll
            for (int r = 0; r < 4; ++r) cb[r] = row[blk * 16 + rq * 4 + r];
            #pragma unroll
            for (int r = 0; r < 4; ++r)
                #pragma unroll
                for (int q = 0; q < 4; ++q) {
                    accM[r][4 * q + 0] = fmaf(cb[r], av[q].x, accM[r][4 * q + 0]);
                    accM[r][4 * q + 1] = fmaf(cb[r], av[q].y, accM[r][4 * q + 1]);
                    accM[r][4 * q + 2] = fmaf(cb[r], av[q].z, accM[r][4 * q + 2]);
                    accM[r][4 * q + 3] = fmaf(cb[r], av[q].w, accM[r][4 * q + 3]);
                }
        }
        __syncthreads();
    }

    grid.sync();   // single cg sync: publishes init lines + flags grid-wide

    // own rt@0 into LDS (after precompute released abuf)
    if (tid < 8) abuf[blk * 8 + tid] = bv[tid];

    // x tag t: consumed value; producers publish tag t+1.  t runs 0..2000.
    unsigned t = 0;
    STAGE_X(0u)    // stage x@0 once; inner-0 of each outer reuses prior stage

    for (int outer = 0; outer < MAX_ITERS_C; ++outer) {
        // ---- w-phase: wl = (A^T rt)[16b..16b+16), rt via flag+read-once ----
        {
            const int pb = tid >> 2;
            if (pb != blk) {
                while (aldu(&flagR[pb]) < (unsigned)outer)
                    __builtin_amdgcn_s_sleep(1);
                asm volatile("" ::: "memory");
                float2 v = u2f(ald64(rtL + (pb << 2) + (tid & 3)));
                abuf[(pb << 3) + ((tid & 3) << 1)]     = v.x;
                abuf[(pb << 3) + ((tid & 3) << 1) + 1] = v.y;
            }
        }
        __syncthreads();
        {
            const int p = tid >> 2, gq = tid & 3;
            float4 acc = {0.f, 0.f, 0.f, 0.f};
            #pragma unroll
            for (int k2 = 0; k2 < 8; ++k2) {
                const int i = p + 256 * k2;
                const float tv = abuf[i];
                float4 a = A4[(size_t)i * 1024 + blk * 4 + gq];
                acc.x = fmaf(a.x, tv, acc.x); acc.y = fmaf(a.y, tv, acc.y);
                acc.z = fmaf(a.z, tv, acc.z); acc.w = fmaf(a.w, tv, acc.w);
            }
            #pragma unroll
            for (int off = 4; off < 64; off <<= 1) {
                acc.x += __shfl_xor(acc.x, off);
                acc.y += __shfl_xor(acc.y, off);
                acc.z += __shfl_xor(acc.z, off);
                acc.w += __shfl_xor(acc.w, off);
            }
            if ((lane >> 2) == 0) gred[wave * 4 + gq] = acc;
        }
        __syncthreads();
        if (tid < 4) {
            float4 tot = {0.f, 0.f, 0.f, 0.f};
            #pragma unroll
            for (int w = 0; w < 16; ++w) {
                float4 v = gred[w * 4 + tid];
                tot.x += v.x; tot.y += v.y; tot.z += v.z; tot.w += v.w;
            }
            wl[tid * 4 + 0] = tot.x; wl[tid * 4 + 1] = tot.y;
            wl[tid * 4 + 2] = tot.z; wl[tid * 4 + 3] = tot.w;
        }
        __syncthreads();

        // ---- inner PGD: x <- relu(x - step*(c + rho*(Mx - wl))) ----
        for (int inner = 0; inner < INNER_C; ++inner) {
            if (inner != 0) { STAGE_X(t) }   // inner 0: xs4 already holds x@t

            float4 xq[4];
            #pragma unroll
            for (int q = 0; q < 4; ++q)
                xq[q] = xs4[256 * cgp + 64 * q + lane];

            float4 pd = {0.f, 0.f, 0.f, 0.f};
            #pragma unroll
            for (int q = 0; q < 4; ++q) {
                pd.x = fmaf(accM[0][4*q+0], xq[q].x, pd.x);
                pd.x = fmaf(accM[0][4*q+1], xq[q].y, pd.x);
                pd.x = fmaf(accM[0][4*q+2], xq[q].z, pd.x);
                pd.x = fmaf(accM[0][4*q+3], xq[q].w, pd.x);
                pd.y = fmaf(accM[1][4*q+0], xq[q].x, pd.y);
                pd.y = fmaf(accM[1][4*q+1], xq[q].y, pd.y);
                pd.y = fmaf(accM[1][4*q+2], xq[q].z, pd.y);
                pd.y = fmaf(accM[1][4*q+3], xq[q].w, pd.y);
                pd.z = fmaf(accM[2][4*q+0], xq[q].x, pd.z);
                pd.z = fmaf(accM[2][4*q+1], xq[q].y, pd.z);
                pd.z = fmaf(accM[2][4*q+2], xq[q].z, pd.z);
                pd.z = fmaf(accM[2][4*q+3], xq[q].w, pd.z);
                pd.w = fmaf(accM[3][4*q+0], xq[q].x, pd.w);
                pd.w = fmaf(accM[3][4*q+1], xq[q].y, pd.w);
                pd.w = fmaf(accM[3][4*q+2], xq[q].z, pd.w);
                pd.w = fmaf(accM[3][4*q+3], xq[q].w, pd.w);
            }

            #pragma unroll
            for (int off = 32; off; off >>= 1) {
                pd.x += __shfl_xor(pd.x, off);
                pd.y += __shfl_xor(pd.y, off);
                pd.z += __shfl_xor(pd.z, off);
                pd.w += __shfl_xor(pd.w, off);
            }
            if (lane == 0) {
                red[cgp][rq * 4 + 0] = pd.x;
                red[cgp][rq * 4 + 1] = pd.y;
                red[cgp][rq * 4 + 2] = pd.z;
                red[cgp][rq * 4 + 3] = pd.w;
            }
            __syncthreads();

            // single-thread tail: compute 16 new x, write LDS copy, publish
            // 64-B line, release (vmcnt drain), bump flag. Other threads go
            // straight to the next STAGE_X poll.
            if (tid == 0) {
                float xn[16];
                #pragma unroll
                for (int j = 0; j < 16; ++j) {
                    const float y = red[0][j] + red[1][j]
                                  + red[2][j] + red[3][j];
                    const float g = cw[j] + RHO_C * (y - wl[j]);
                    float v = xs[blk * 16 + j] - STEP_C * g;
                    xn[j] = v > 0.f ? v : 0.f;
                }
                #pragma unroll
                for (int j = 0; j < 16; ++j) xs[blk * 16 + j] = xn[j];
                unsigned long long* dst =
                    xL + (((t + 1u) & 1u) ? 2048u : 0u) + (blk << 3);
                #pragma unroll
                for (int j = 0; j < 8; ++j)
                    ast64(dst + j, f2u(xn[2 * j], xn[2 * j + 1]));
                asm volatile("s_waitcnt vmcnt(0)" ::: "memory");
                astu(&flagX[blk], t + 1u);
            }
            ++t;   // no grid barrier: the flag IS the sync
        }

        // ---- Ax on own 8 rows + s,u,rt update; x@t via flag+read-once ----
        STAGE_X(t)
        {
            const int r = blk * 8 + (wave >> 1), h = wave & 1;
            const float4* Ar = A4 + (size_t)r * 1024 + h * 512;
            const float4* xh = xs4 + h * 512;
            float4 acc = {0.f, 0.f, 0.f, 0.f};
            #pragma unroll
            for (int it = 0; it < 8; ++it) {
                float4 a = Ar[it * 64 + lane], xv = xh[it * 64 + lane];
                acc.x = fmaf(a.x, xv.x, acc.x); acc.y = fmaf(a.y, xv.y, acc.y);
                acc.z = fmaf(a.z, xv.z, acc.z); acc.w = fmaf(a.w, xv.w, acc.w);
            }
            float d = acc.x + acc.y + acc.z + acc.w;
            #pragma unroll
            for (int off = 32; off; off >>= 1) d += __shfl_xor(d, off);
            if (lane == 0) tpart[wave] = d;
        }
        __syncthreads();
        if (tid == 0) {
            float rtv[8];
            #pragma unroll
            for (int j = 0; j < 8; ++j) {
                const float a  = tpart[2 * j] + tpart[2 * j + 1];
                const float bb = bv[j];
                const float uu = uv[j];
                float sn = a - bb + uu; sn = sn > 0.f ? sn : 0.f;
                const float un = uu + a - sn - bb;
                sv[j] = sn; uv[j] = un;
                rtv[j] = sn + bb - un;
                abuf[blk * 8 + j] = rtv[j];        // own rt in LDS for w-phase
            }
            #pragma unroll
            for (int j = 0; j < 4; ++j)
                ast64(rtL + (blk << 2) + j, f2u(rtv[2 * j], rtv[2 * j + 1]));
            asm volatile("s_waitcnt vmcnt(0)" ::: "memory");
            astu(&flagR[blk], (unsigned)outer + 1u);
        }
        // no grid barrier: next outer's flagR poll IS the sync
    }

    // ---- outputs: [x(4096), s(2048), u(2048), -u(2048)] ----
    __syncthreads();   // sv/uv/xs written by thread 0 in the last outer
    if (tid < 16) out[blk * 16 + tid] = xs[blk * 16 + tid];
    if (tid < 8) {
        const int i = blk * 8 + tid;
        out[4096 + i] = sv[tid];
        out[6144 + i] = uv[tid];
        out[8192 + i] = -uv[tid];
    }
}

extern "C" void kernel_launch(void* const* d_in, const int* in_sizes, int n_in,
                              void* d_out, int out_size, void* d_ws, size_t ws_size,
                              hipStream_t stream) {
    const float* A    = (const float*)d_in[0];   // 2048*4096
    const float* bvec = (const float*)d_in[1];   // 2048
    const float* cvec = (const float*)d_in[2];   // 4096
    float* out = (float*)d_out;

    unsigned long long* xL  = (unsigned long long*)d_ws;   // 2*256*8 u64 = 32 KB
    unsigned long long* rtL = xL + 2 * 2048;               // 256*4  u64 =  8 KB
    unsigned* flagX = (unsigned*)(rtL + 1024);             // 256 u32 = 1 KB
    unsigned* flagR = flagX + 256;                         // 256 u32 = 1 KB

    void* args[] = { (void*)&A, (void*)&bvec, (void*)&cvec, (void*)&out,
                     (void*)&xL, (void*)&rtL, (void*)&flagX, (void*)&flagR };
    hipError_t err = hipLaunchCooperativeKernel((const void*)admm_flag,
                               dim3(256), dim3(1024), args, 0, stream);
    (void)err;
}

// Round 4
// 15657.999 us; speedup vs baseline: 1.0614x; 1.0614x over previous
//
#include <hip/hip_runtime.h>
#include <hip/hip_cooperative_groups.h>

namespace cg = cooperative_groups;

#define M_ROWS 2048
#define N_COLS 4096
#define RHO_C 1.0f
#define STEP_C 5e-05f
#define MAX_ITERS_C 100
#define INNER_C 20

// Relaxed agent-scope atomics: coherent at the Infinity Cache (sc1 path),
// bypassing per-XCD L2 / per-CU L1 — no cache-op fences needed.
__device__ __forceinline__ float aload(const float* p) {
    return __hip_atomic_load(p, __ATOMIC_RELAXED, __HIP_MEMORY_SCOPE_AGENT);
}
__device__ __forceinline__ void astore(float* p, float v) {
    __hip_atomic_store(p, v, __ATOMIC_RELAXED, __HIP_MEMORY_SCOPE_AGENT);
}
__device__ __forceinline__ float2 aload2(const float* p) {
    unsigned long long v = __hip_atomic_load(
        (const unsigned long long*)p, __ATOMIC_RELAXED,
        __HIP_MEMORY_SCOPE_AGENT);
    union { unsigned long long u; float2 f; } c; c.u = v; return c.f;
}
__device__ __forceinline__ unsigned aldu(const unsigned* p) {
    return __hip_atomic_load(p, __ATOMIC_RELAXED, __HIP_MEMORY_SCOPE_AGENT);
}

// Flat single-counter grid barrier, depth 1 (vs R0's leaf->root->epoch
// depth 3). Caller: thread 0 only, AFTER its own wave's stores are drained
// (s_waitcnt vmcnt(0)). Monotone counter, no resets; exactly one poller
// per block on one line (the proven-quiet polling regime). Last arriver
// skips the poll. Sleepless spin: the dependent-load chain self-paces at
// one MALL RT per iteration (256 pollers x 64 B / RT ~ 23 GB/s — benign).
__device__ __forceinline__ void flat_arrive_wait(unsigned* cnt, unsigned target) {
    unsigned old = __hip_atomic_fetch_add(cnt, 1u, __ATOMIC_RELAXED,
                                          __HIP_MEMORY_SCOPE_AGENT);
    if (old + 1u != target)
        while (aldu(cnt) < target) { }
}

// 256 blocks (1/CU) x 1024 threads (16 waves), persistent cooperative kernel.
// Gram form: g = c + rho*(M x - A^T rt), M = A^T A held ENTIRELY in registers:
// wave w = (cgp=w>>2, rq=w&3); thread (cgp,rq,lane):
//   accM[r][4q+e] = M[16*blk + 4*rq + r][1024*cgp + 256*q + 4*lane + e]
// so each thread's 16 x-operands are 4 contiguous float4s in a 4096-float xs.
// Block b also owns rows [8b,8b+8) of A (Ax/s,u,rt) and x entries [16b,16b+16).
__global__ __launch_bounds__(1024) void admm_flat(
    const float* __restrict__ A, const float* __restrict__ bvec,
    const float* __restrict__ cvec, float* __restrict__ out,
    float* __restrict__ x0, float* __restrict__ x1,
    float* __restrict__ rt, unsigned* __restrict__ bstate)
{
    cg::grid_group grid = cg::this_grid();
    const int tid  = threadIdx.x;
    const int blk  = blockIdx.x;
    const int lane = tid & 63;
    const int wave = tid >> 6;
    const int cgp  = wave >> 2;   // col-group: cols [1024*cgp, +1024)
    const int rq   = wave & 3;    // row-quad : rows 16*blk + 4*rq .. +4

    __shared__ float  abuf[4 * N_COLS];  // 64 KB staging (A rows / rt)
    __shared__ float4 xs4[1024];         // 16 KB staged x (and Ax-phase x)
    __shared__ float  red[4][16];        // per-colgroup row partials
    __shared__ float4 gred[64];          // w-phase reduce scratch
    __shared__ float  wl[16], cw[16];
    __shared__ float  sv[8], uv[8], tpart[16];

    float* xs = reinterpret_cast<float*>(xs4);
    const float4* A4 = reinterpret_cast<const float4*>(A);
    float4* abuf4 = reinterpret_cast<float4*>(abuf);

    // ---- init ----
    if (tid < 16) {
        cw[tid] = cvec[blk * 16 + tid];
        astore(&x0[blk * 16 + tid], 0.0f);
    }
    if (tid < 8) {
        sv[tid] = 0.0f; uv[tid] = 0.0f;
        astore(&rt[blk * 8 + tid], bvec[blk * 8 + tid]);
    }
    if (blk == 0 && tid < 320) bstate[tid] = 0u;

    // ---- precompute register-resident M fragment ----
    float accM[4][16];
    #pragma unroll
    for (int r = 0; r < 4; ++r)
        #pragma unroll
        for (int k = 0; k < 16; ++k) accM[r][k] = 0.0f;

    for (int i0 = 0; i0 < M_ROWS; i0 += 4) {
        #pragma unroll
        for (int ii = 0; ii < 4; ++ii)
            abuf4[ii * 1024 + tid] = A4[(size_t)(i0 + ii) * 1024 + tid];
        __syncthreads();
        #pragma unroll
        for (int ii = 0; ii < 4; ++ii) {
            const float*  row  = abuf + ii * N_COLS;
            const float4* row4 = abuf4 + ii * 1024;
            float4 av[4];
            #pragma unroll
            for (int q = 0; q < 4; ++q)
                av[q] = row4[256 * cgp + 64 * q + lane];
            float cb[4];
            #pragma unroll
            for (int r = 0; r < 4; ++r) cb[r] = row[blk * 16 + rq * 4 + r];
            #pragma unroll
            for (int r = 0; r < 4; ++r)
                #pragma unroll
                for (int q = 0; q < 4; ++q) {
                    accM[r][4 * q + 0] = fmaf(cb[r], av[q].x, accM[r][4 * q + 0]);
                    accM[r][4 * q + 1] = fmaf(cb[r], av[q].y, accM[r][4 * q + 1]);
                    accM[r][4 * q + 2] = fmaf(cb[r], av[q].z, accM[r][4 * q + 2]);
                    accM[r][4 * q + 3] = fmaf(cb[r], av[q].w, accM[r][4 * q + 3]);
                }
        }
        __syncthreads();
    }

    grid.sync();   // single cg sync: publishes x0/rt/bstate
    unsigned* bcnt = bstate;   // one 4-B flat counter, one line
    unsigned bar_n = 0;        // rounds completed

    for (int outer = 0; outer < MAX_ITERS_C; ++outer) {
        // ---- w-phase (block-local result): wl = (A^T rt)[16b..16b+16) ----
        abuf[tid]        = aload(&rt[tid]);
        abuf[tid + 1024] = aload(&rt[tid + 1024]);
        __syncthreads();
        {
            const int p = tid >> 2, gq = tid & 3;
            float4 acc = {0.f, 0.f, 0.f, 0.f};
            #pragma unroll
            for (int k2 = 0; k2 < 8; ++k2) {
                const int i = p + 256 * k2;
                const float tv = abuf[i];
                float4 a = A4[(size_t)i * 1024 + blk * 4 + gq];
                acc.x = fmaf(a.x, tv, acc.x); acc.y = fmaf(a.y, tv, acc.y);
                acc.z = fmaf(a.z, tv, acc.z); acc.w = fmaf(a.w, tv, acc.w);
            }
            #pragma unroll
            for (int off = 4; off < 64; off <<= 1) {
                acc.x += __shfl_xor(acc.x, off);
                acc.y += __shfl_xor(acc.y, off);
                acc.z += __shfl_xor(acc.z, off);
                acc.w += __shfl_xor(acc.w, off);
            }
            if ((lane >> 2) == 0) gred[wave * 4 + gq] = acc;
        }
        __syncthreads();
        if (tid < 4) {
            float4 tot = {0.f, 0.f, 0.f, 0.f};
            #pragma unroll
            for (int w = 0; w < 16; ++w) {
                float4 v = gred[w * 4 + tid];
                tot.x += v.x; tot.y += v.y; tot.z += v.z; tot.w += v.w;
            }
            wl[tid * 4 + 0] = tot.x; wl[tid * 4 + 1] = tot.y;
            wl[tid * 4 + 2] = tot.z; wl[tid * 4 + 3] = tot.w;
        }
        __syncthreads();

        // ---- inner PGD: x <- relu(x - step*(c + rho*(Mx - wl))) ----
        for (int inner = 0; inner < INNER_C; ++inner) {
            const float* xsrc = (inner & 1) ? x1 : x0;
            float*       xdst = (inner & 1) ? x0 : x1;

            // coherent vectorized x-exchange: 16 B per thread, once
            {
                float2 lo = aload2(xsrc + 4 * tid);
                float2 hi = aload2(xsrc + 4 * tid + 2);
                xs4[tid] = make_float4(lo.x, lo.y, hi.x, hi.y);
            }
            __syncthreads();                       // (A) xs4 staged

            float4 xq[4];
            #pragma unroll
            for (int q = 0; q < 4; ++q)
                xq[q] = xs4[256 * cgp + 64 * q + lane];

            float4 pd = {0.f, 0.f, 0.f, 0.f};
            #pragma unroll
            for (int q = 0; q < 4; ++q) {
                pd.x = fmaf(accM[0][4*q+0], xq[q].x, pd.x);
                pd.x = fmaf(accM[0][4*q+1], xq[q].y, pd.x);
                pd.x = fmaf(accM[0][4*q+2], xq[q].z, pd.x);
                pd.x = fmaf(accM[0][4*q+3], xq[q].w, pd.x);
                pd.y = fmaf(accM[1][4*q+0], xq[q].x, pd.y);
                pd.y = fmaf(accM[1][4*q+1], xq[q].y, pd.y);
                pd.y = fmaf(accM[1][4*q+2], xq[q].z, pd.y);
                pd.y = fmaf(accM[1][4*q+3], xq[q].w, pd.y);
                pd.z = fmaf(accM[2][4*q+0], xq[q].x, pd.z);
                pd.z = fmaf(accM[2][4*q+1], xq[q].y, pd.z);
                pd.z = fmaf(accM[2][4*q+2], xq[q].z, pd.z);
                pd.z = fmaf(accM[2][4*q+3], xq[q].w, pd.z);
                pd.w = fmaf(accM[3][4*q+0], xq[q].x, pd.w);
                pd.w = fmaf(accM[3][4*q+1], xq[q].y, pd.w);
                pd.w = fmaf(accM[3][4*q+2], xq[q].z, pd.w);
                pd.w = fmaf(accM[3][4*q+3], xq[q].w, pd.w);
            }

            #pragma unroll
            for (int off = 32; off; off >>= 1) {
                pd.x += __shfl_xor(pd.x, off);
                pd.y += __shfl_xor(pd.y, off);
                pd.z += __shfl_xor(pd.z, off);
                pd.w += __shfl_xor(pd.w, off);
            }
            if (lane == 0) {
                red[cgp][rq * 4 + 0] = pd.x;
                red[cgp][rq * 4 + 1] = pd.y;
                red[cgp][rq * 4 + 2] = pd.z;
                red[cgp][rq * 4 + 3] = pd.w;
            }
            __syncthreads();                       // (B) red ready

            // producers = lanes 0..15 of wave 0; thread 0's wave-scope
            // vmcnt(0) drains ALL 16 lanes' stores, then depth-1 arrive.
            if (tid < 16) {
                const float y = red[0][tid] + red[1][tid]
                              + red[2][tid] + red[3][tid];
                const float g = cw[tid] + RHO_C * (y - wl[tid]);
                float xn = xs[blk * 16 + tid] - STEP_C * g;
                xn = xn > 0.f ? xn : 0.f;
                astore(&xdst[blk * 16 + tid], xn);
            }
            if (tid == 0) {
                asm volatile("s_waitcnt vmcnt(0)" ::: "memory");
                flat_arrive_wait(bcnt, 256u * (bar_n + 1u));
            }
            ++bar_n;
            __syncthreads();                       // (C) grid release
        }
        // INNER_C even -> final x is in x0

        // ---- Ax on own 8 rows + s,u,rt update (block-local) ----
        {
            float2 lo = aload2(x0 + 4 * tid);
            float2 hi = aload2(x0 + 4 * tid + 2);
            xs4[tid] = make_float4(lo.x, lo.y, hi.x, hi.y);
        }
        __syncthreads();
        {
            const int r = blk * 8 + (wave >> 1), h = wave & 1;
            const float4* Ar = A4 + (size_t)r * 1024 + h * 512;
            const float4* xh = xs4 + h * 512;
            float4 acc = {0.f, 0.f, 0.f, 0.f};
            #pragma unroll
            for (int it = 0; it < 8; ++it) {
                float4 a = Ar[it * 64 + lane], xv = xh[it * 64 + lane];
                acc.x = fmaf(a.x, xv.x, acc.x); acc.y = fmaf(a.y, xv.y, acc.y);
                acc.z = fmaf(a.z, xv.z, acc.z); acc.w = fmaf(a.w, xv.w, acc.w);
            }
            float d = acc.x + acc.y + acc.z + acc.w;
            #pragma unroll
            for (int off = 32; off; off >>= 1) d += __shfl_xor(d, off);
            if (lane == 0) tpart[wave] = d;
        }
        __syncthreads();
        if (tid < 8) {
            const int i = blk * 8 + tid;
            const float a  = tpart[2 * tid] + tpart[2 * tid + 1];
            const float bb = bvec[i];
            const float uu = uv[tid];
            float sn = a - bb + uu; sn = sn > 0.f ? sn : 0.f;
            const float un = uu + a - sn - bb;
            sv[tid] = sn; uv[tid] = un;
            astore(&rt[i], sn + bb - un);
        }
        if (tid == 0) {
            asm volatile("s_waitcnt vmcnt(0)" ::: "memory");
            flat_arrive_wait(bcnt, 256u * (bar_n + 1u));
        }
        ++bar_n;
        __syncthreads();                           // grid release
    }

    // ---- outputs: [x(4096), s(2048), u(2048), -u(2048)] ----
    if (tid < 16) out[blk * 16 + tid] = aload(&x0[blk * 16 + tid]);
    if (tid < 8) {
        const int i = blk * 8 + tid;
        out[4096 + i] = sv[tid];
        out[6144 + i] = uv[tid];
        out[8192 + i] = -uv[tid];
    }
}

extern "C" void kernel_launch(void* const* d_in, const int* in_sizes, int n_in,
                              void* d_out, int out_size, void* d_ws, size_t ws_size,
                              hipStream_t stream) {
    const float* A    = (const float*)d_in[0];   // 2048*4096
    const float* bvec = (const float*)d_in[1];   // 2048
    const float* cvec = (const float*)d_in[2];   // 4096
    float* out = (float*)d_out;

    float* ws = (float*)d_ws;
    float* x0 = ws;                    // 4096
    float* x1 = ws + 4096;             // 4096
    float* rt = ws + 8192;             // 2048
    unsigned* bstate = (unsigned*)(ws + 12288);  // 320 uints (only [0] used)

    void* args[] = { (void*)&A, (void*)&bvec, (void*)&cvec, (void*)&out,
                     (void*)&x0, (void*)&x1, (void*)&rt, (void*)&bstate };
    hipError_t err = hipLaunchCooperativeKernel((const void*)admm_flat,
                               dim3(256), dim3(1024), args, 0, stream);
    (void)err;
}

// Round 5
// 12582.780 us; speedup vs baseline: 1.3207x; 1.2444x over previous
//
#include <hip/hip_runtime.h>
#include <hip/hip_cooperative_groups.h>

namespace cg = cooperative_groups;

#define M_ROWS 2048
#define N_COLS 4096
#define RHO_C 1.0f
#define STEP_C 5e-05f
#define MAX_ITERS_C 100
#define INNER_C 20

// Relaxed agent-scope atomics: coherent at the Infinity Cache (sc1 path),
// bypassing per-XCD L2 / per-CU L1 — no cache-op fences needed.
__device__ __forceinline__ float aload(const float* p) {
    return __hip_atomic_load(p, __ATOMIC_RELAXED, __HIP_MEMORY_SCOPE_AGENT);
}
__device__ __forceinline__ unsigned aldu(const unsigned* p) {
    return __hip_atomic_load(p, __ATOMIC_RELAXED, __HIP_MEMORY_SCOPE_AGENT);
}
__device__ __forceinline__ void astu(unsigned* p, unsigned v) {
    __hip_atomic_store(p, v, __ATOMIC_RELAXED, __HIP_MEMORY_SCOPE_AGENT);
}

// Wide (16-B) coherent messages: one fabric transaction instead of 2-4.
// sc0+sc1 = strongest scope (system): never weaker than the proven 4/8-B
// agent ops. Single-line access => per-dword atomicity (all we need: every
// dword has exactly one producer).
typedef __attribute__((ext_vector_type(4))) float f32x4;
__device__ __forceinline__ f32x4 aload4(const float* p) {
    f32x4 v;
    asm volatile("global_load_dwordx4 %0, %1, off sc0 sc1\n\t"
                 "s_waitcnt vmcnt(0)"
                 : "=&v"(v) : "v"(p) : "memory");
    return v;
}
__device__ __forceinline__ void astore4(float* p, f32x4 v) {
    asm volatile("global_store_dwordx4 %0, %1, off sc0 sc1"
                 :: "v"(p), "v"(v) : "memory");
}

// Depth-2 grid barrier (R0's tree minus the redundant epoch hop).
// Arrivals RMW 8 spread leaf lines (32 RMWs each, parallel at the MALL);
// each leaf completer RMWs the root; pollers poll root >= 8*(n+1).
// Root line receives only 8 RMWs/round -> stays in the quiet-poll regime
// (R4 lesson: 256 RMWs + sleepless pollers on one line serialize ~+2.3us).
// Monotonic counters, no resets; s_sleep(1) backoff as in R0.
__device__ inline void tree2_barrier(unsigned* bs, int blk, unsigned n) {
    __syncthreads();   // compiler emits vmcnt(0) drain per wave before barrier
    if (threadIdx.x == 0) {
        asm volatile("s_waitcnt vmcnt(0)" ::: "memory");   // belt & braces
        unsigned* leaf = bs + ((blk & 7) << 5);            // 128-B spread
        unsigned* root = bs + 256;
        unsigned old = __hip_atomic_fetch_add(leaf, 1u, __ATOMIC_RELAXED,
                                              __HIP_MEMORY_SCOPE_AGENT);
        if (old == n * 32u + 31u)
            __hip_atomic_fetch_add(root, 1u, __ATOMIC_RELAXED,
                                   __HIP_MEMORY_SCOPE_AGENT);
        while (aldu(root) < n * 8u + 8u)
            __builtin_amdgcn_s_sleep(1);
        asm volatile("" ::: "memory");
    }
    __syncthreads();
}

// 256 blocks (1/CU) x 1024 threads (16 waves), persistent cooperative kernel.
// Gram form: g = c + rho*(M x - A^T rt), M = A^T A held ENTIRELY in registers:
// wave w = (cgp=w>>2, rq=w&3); thread (cgp,rq,lane):
//   accM[r][4q+e] = M[16*blk + 4*rq + r][1024*cgp + 256*q + 4*lane + e]
// so each thread's 16 x-operands are 4 contiguous float4s in a 4096-float xs.
// Block b also owns rows [8b,8b+8) of A (Ax/s,u,rt) and x entries [16b,16b+16).
__global__ __launch_bounds__(1024) void admm_r5(
    const float* __restrict__ A, const float* __restrict__ bvec,
    const float* __restrict__ cvec, float* __restrict__ out,
    float* __restrict__ x0, float* __restrict__ x1,
    float* __restrict__ rt, unsigned* __restrict__ bstate)
{
    cg::grid_group grid = cg::this_grid();
    const int tid  = threadIdx.x;
    const int blk  = blockIdx.x;
    const int lane = tid & 63;
    const int wave = tid >> 6;
    const int cgp  = wave >> 2;   // col-group: cols [1024*cgp, +1024)
    const int rq   = wave & 3;    // row-quad : rows 16*blk + 4*rq .. +4

    __shared__ float  abuf[4 * N_COLS];  // 64 KB staging (A rows / rt)
    __shared__ float4 xs4[1024];         // 16 KB staged x (and Ax-phase x)
    __shared__ float  red[4][16];        // per-colgroup row partials
    __shared__ float4 gred[64];          // w-phase reduce scratch
    __shared__ float  wl[16], cw[16];
    __shared__ float  sv[8], uv[8], tpart[16];

    float* xs = reinterpret_cast<float*>(xs4);
    const float4* A4 = reinterpret_cast<const float4*>(A);
    float4* abuf4 = reinterpret_cast<float4*>(abuf);

    // ---- init ----
    if (tid < 16) {
        cw[tid] = cvec[blk * 16 + tid];
        __hip_atomic_store(&x0[blk * 16 + tid], 0.0f, __ATOMIC_RELAXED,
                           __HIP_MEMORY_SCOPE_AGENT);
    }
    if (tid < 8) {
        sv[tid] = 0.0f; uv[tid] = 0.0f;
        __hip_atomic_store(&rt[blk * 8 + tid], bvec[blk * 8 + tid],
                           __ATOMIC_RELAXED, __HIP_MEMORY_SCOPE_AGENT);
    }
    if (blk == 0 && tid < 320) astu(&bstate[tid], 0u);

    // ---- precompute register-resident M fragment ----
    float accM[4][16];
    #pragma unroll
    for (int r = 0; r < 4; ++r)
        #pragma unroll
        for (int k = 0; k < 16; ++k) accM[r][k] = 0.0f;

    for (int i0 = 0; i0 < M_ROWS; i0 += 4) {
        #pragma unroll
        for (int ii = 0; ii < 4; ++ii)
            abuf4[ii * 1024 + tid] = A4[(size_t)(i0 + ii) * 1024 + tid];
        __syncthreads();
        #pragma unroll
        for (int ii = 0; ii < 4; ++ii) {
            const float*  row  = abuf + ii * N_COLS;
            const float4* row4 = abuf4 + ii * 1024;
            float4 av[4];
            #pragma unroll
            for (int q = 0; q < 4; ++q)
                av[q] = row4[256 * cgp + 64 * q + lane];
            float cb[4];
            #pragma unroll
            for (int r = 0; r < 4; ++r) cb[r] = row[blk * 16 + rq * 4 + r];
            #pragma unroll
            for (int r = 0; r < 4; ++r)
                #pragma unroll
                for (int q = 0; q < 4; ++q) {
                    accM[r][4 * q + 0] = fmaf(cb[r], av[q].x, accM[r][4 * q + 0]);
                    accM[r][4 * q + 1] = fmaf(cb[r], av[q].y, accM[r][4 * q + 1]);
                    accM[r][4 * q + 2] = fmaf(cb[r], av[q].z, accM[r][4 * q + 2]);
                    accM[r][4 * q + 3] = fmaf(cb[r], av[q].w, accM[r][4 * q + 3]);
                }
        }
        __syncthreads();
    }

    grid.sync();   // single cg sync: publishes x0/rt/bstate
    unsigned bar_n = 0;

    for (int outer = 0; outer < MAX_ITERS_C; ++outer) {
        // ---- w-phase (block-local result): wl = (A^T rt)[16b..16b+16) ----
        if (tid < 512) {
            f32x4 v = aload4(rt + 4 * tid);
            abuf4[tid] = make_float4(v.x, v.y, v.z, v.w);
        }
        __syncthreads();
        {
            const int p = tid >> 2, gq = tid & 3;
            float4 acc = {0.f, 0.f, 0.f, 0.f};
            #pragma unroll
            for (int k2 = 0; k2 < 8; ++k2) {
                const int i = p + 256 * k2;
                const float tv = abuf[i];
                float4 a = A4[(size_t)i * 1024 + blk * 4 + gq];
                acc.x = fmaf(a.x, tv, acc.x); acc.y = fmaf(a.y, tv, acc.y);
                acc.z = fmaf(a.z, tv, acc.z); acc.w = fmaf(a.w, tv, acc.w);
            }
            #pragma unroll
            for (int off = 4; off < 64; off <<= 1) {
                acc.x += __shfl_xor(acc.x, off);
                acc.y += __shfl_xor(acc.y, off);
                acc.z += __shfl_xor(acc.z, off);
                acc.w += __shfl_xor(acc.w, off);
            }
            if ((lane >> 2) == 0) gred[wave * 4 + gq] = acc;
        }
        __syncthreads();
        if (tid < 4) {
            float4 tot = {0.f, 0.f, 0.f, 0.f};
            #pragma unroll
            for (int w = 0; w < 16; ++w) {
                float4 v = gred[w * 4 + tid];
                tot.x += v.x; tot.y += v.y; tot.z += v.z; tot.w += v.w;
            }
            wl[tid * 4 + 0] = tot.x; wl[tid * 4 + 1] = tot.y;
            wl[tid * 4 + 2] = tot.z; wl[tid * 4 + 3] = tot.w;
        }
        __syncthreads();

        // ---- inner PGD: x <- relu(x - step*(c + rho*(Mx - wl))) ----
        for (int inner = 0; inner < INNER_C; ++inner) {
            const float* xsrc = (inner & 1) ? x1 : x0;
            float*       xdst = (inner & 1) ? x0 : x1;

            // coherent vectorized x-exchange: ONE 16-B message per thread
            {
                f32x4 v = aload4(xsrc + 4 * tid);
                xs4[tid] = make_float4(v.x, v.y, v.z, v.w);
            }
            __syncthreads();                       // (A) xs4 staged

            float4 xq[4];
            #pragma unroll
            for (int q = 0; q < 4; ++q)
                xq[q] = xs4[256 * cgp + 64 * q + lane];

            float4 pd = {0.f, 0.f, 0.f, 0.f};
            #pragma unroll
            for (int q = 0; q < 4; ++q) {
                pd.x = fmaf(accM[0][4*q+0], xq[q].x, pd.x);
                pd.x = fmaf(accM[0][4*q+1], xq[q].y, pd.x);
                pd.x = fmaf(accM[0][4*q+2], xq[q].z, pd.x);
                pd.x = fmaf(accM[0][4*q+3], xq[q].w, pd.x);
                pd.y = fmaf(accM[1][4*q+0], xq[q].x, pd.y);
                pd.y = fmaf(accM[1][4*q+1], xq[q].y, pd.y);
                pd.y = fmaf(accM[1][4*q+2], xq[q].z, pd.y);
                pd.y = fmaf(accM[1][4*q+3], xq[q].w, pd.y);
                pd.z = fmaf(accM[2][4*q+0], xq[q].x, pd.z);
                pd.z = fmaf(accM[2][4*q+1], xq[q].y, pd.z);
                pd.z = fmaf(accM[2][4*q+2], xq[q].z, pd.z);
                pd.z = fmaf(accM[2][4*q+3], xq[q].w, pd.z);
                pd.w = fmaf(accM[3][4*q+0], xq[q].x, pd.w);
                pd.w = fmaf(accM[3][4*q+1], xq[q].y, pd.w);
                pd.w = fmaf(accM[3][4*q+2], xq[q].z, pd.w);
                pd.w = fmaf(accM[3][4*q+3], xq[q].w, pd.w);
            }

            #pragma unroll
            for (int off = 32; off; off >>= 1) {
                pd.x += __shfl_xor(pd.x, off);
                pd.y += __shfl_xor(pd.y, off);
                pd.z += __shfl_xor(pd.z, off);
                pd.w += __shfl_xor(pd.w, off);
            }
            if (lane == 0) {
                red[cgp][rq * 4 + 0] = pd.x;
                red[cgp][rq * 4 + 1] = pd.y;
                red[cgp][rq * 4 + 2] = pd.z;
                red[cgp][rq * 4 + 3] = pd.w;
            }
            __syncthreads();                       // (B) red ready

            // producers: 4 threads x one 16-B store (fewer fabric messages)
            if (tid < 4) {
                auto xup = [&](int j) -> float {
                    const float y = red[0][j] + red[1][j]
                                  + red[2][j] + red[3][j];
                    const float g = cw[j] + RHO_C * (y - wl[j]);
                    float xn = xs[blk * 16 + j] - STEP_C * g;
                    return xn > 0.f ? xn : 0.f;
                };
                const int j0 = 4 * tid;
                f32x4 xv;
                xv.x = xup(j0);     xv.y = xup(j0 + 1);
                xv.z = xup(j0 + 2); xv.w = xup(j0 + 3);
                astore4(&xdst[blk * 16 + j0], xv);
            }
            tree2_barrier(bstate, blk, bar_n); ++bar_n;
        }
        // INNER_C even -> final x is in x0

        // ---- Ax on own 8 rows + s,u,rt update (block-local) ----
        {
            f32x4 v = aload4(x0 + 4 * tid);
            xs4[tid] = make_float4(v.x, v.y, v.z, v.w);
        }
        __syncthreads();
        {
            const int r = blk * 8 + (wave >> 1), h = wave & 1;
            const float4* Ar = A4 + (size_t)r * 1024 + h * 512;
            const float4* xh = xs4 + h * 512;
            float4 acc = {0.f, 0.f, 0.f, 0.f};
            #pragma unroll
            for (int it = 0; it < 8; ++it) {
                float4 a = Ar[it * 64 + lane], xv = xh[it * 64 + lane];
                acc.x = fmaf(a.x, xv.x, acc.x); acc.y = fmaf(a.y, xv.y, acc.y);
                acc.z = fmaf(a.z, xv.z, acc.z); acc.w = fmaf(a.w, xv.w, acc.w);
            }
            float d = acc.x + acc.y + acc.z + acc.w;
            #pragma unroll
            for (int off = 32; off; off >>= 1) d += __shfl_xor(d, off);
            if (lane == 0) tpart[wave] = d;
        }
        __syncthreads();
        if (tid < 2) {
            auto rowup = [&](int j) -> float {
                const float a  = tpart[2 * j] + tpart[2 * j + 1];
                const float bb = bvec[blk * 8 + j];
                const float uu = uv[j];
                float sn = a - bb + uu; sn = sn > 0.f ? sn : 0.f;
                const float un = uu + a - sn - bb;
                sv[j] = sn; uv[j] = un;
                return sn + bb - un;
            };
            const int j0 = 4 * tid;
            f32x4 rr;
            rr.x = rowup(j0);     rr.y = rowup(j0 + 1);
            rr.z = rowup(j0 + 2); rr.w = rowup(j0 + 3);
            astore4(&rt[blk * 8 + j0], rr);
        }
        tree2_barrier(bstate, blk, bar_n); ++bar_n;
    }

    // ---- outputs: [x(4096), s(2048), u(2048), -u(2048)] ----
    if (tid < 16) out[blk * 16 + tid] = aload(&x0[blk * 16 + tid]);
    if (tid < 8) {
        const int i = blk * 8 + tid;
        out[4096 + i] = sv[tid];
        out[6144 + i] = uv[tid];
        out[8192 + i] = -uv[tid];
    }
}

extern "C" void kernel_launch(void* const* d_in, const int* in_sizes, int n_in,
                              void* d_out, int out_size, void* d_ws, size_t ws_size,
                              hipStream_t stream) {
    const float* A    = (const float*)d_in[0];   // 2048*4096
    const float* bvec = (const float*)d_in[1];   // 2048
    const float* cvec = (const float*)d_in[2];   // 4096
    float* out = (float*)d_out;

    float* ws = (float*)d_ws;
    float* x0 = ws;                    // 4096
    float* x1 = ws + 4096;             // 4096
    float* rt = ws + 8192;             // 2048
    unsigned* bstate = (unsigned*)(ws + 12288);  // 320 uints

    void* args[] = { (void*)&A, (void*)&bvec, (void*)&cvec, (void*)&out,
                     (void*)&x0, (void*)&x1, (void*)&rt, (void*)&bstate };
    hipError_t err = hipLaunchCooperativeKernel((const void*)admm_r5,
                               dim3(256), dim3(1024), args, 0, stream);
    (void)err;
}

// Round 6
// 11998.583 us; speedup vs baseline: 1.3851x; 1.0487x over previous
//
#include <hip/hip_runtime.h>
#include <hip/hip_cooperative_groups.h>

namespace cg = cooperative_groups;

#define M_ROWS 2048
#define N_COLS 4096
#define RHO_C 1.0f
#define STEP_C 5e-05f
#define MAX_ITERS_C 100
#define INNER_C 20

// Relaxed agent-scope atomics: coherent at the Infinity Cache (sc1 path),
// bypassing per-XCD L2 / per-CU L1 — no cache-op fences needed.
// (R5 lesson: do NOT use sc0+sc1 system-scope asm — FETCH_SIZE +2.5 GB.)
__device__ __forceinline__ float aload(const float* p) {
    return __hip_atomic_load(p, __ATOMIC_RELAXED, __HIP_MEMORY_SCOPE_AGENT);
}
__device__ __forceinline__ void astore(float* p, float v) {
    __hip_atomic_store(p, v, __ATOMIC_RELAXED, __HIP_MEMORY_SCOPE_AGENT);
}
__device__ __forceinline__ float2 aload2(const float* p) {
    unsigned long long v = __hip_atomic_load(
        (const unsigned long long*)p, __ATOMIC_RELAXED,
        __HIP_MEMORY_SCOPE_AGENT);
    union { unsigned long long u; float2 f; } c; c.u = v; return c.f;
}
__device__ __forceinline__ unsigned aldu(const unsigned* p) {
    return __hip_atomic_load(p, __ATOMIC_RELAXED, __HIP_MEMORY_SCOPE_AGENT);
}

// 256 blocks (1/CU) x 1024 threads (16 waves), persistent cooperative kernel.
// Gram form: g = c + rho*(M x - A^T rt), M = A^T A held ENTIRELY in registers:
// wave w = (cgp=w>>2, rq=w&3); thread (cgp,rq,lane):
//   accM[r][4q+e] = M[16*blk + 4*rq + r][1024*cgp + 256*q + 4*lane + e]
// so each thread's 16 x-operands are 4 contiguous float4s in a 4096-float xs.
// Block b also owns rows [8b,8b+8) of A (Ax/s,u,rt) and x entries [16b,16b+16).
//
// Sync per round (depth-2 tree, 3 block barriers):
//   [all] syncthreads (entry; red/tpart ready)
//   [wave0 lanes 0..K] compute + agent-store results
//   [thread0] s_waitcnt vmcnt(0)  (drains the whole wave's stores)
//             leaf RMW (8 spread lines, 32 arrivals each, parallel at MALL)
//             leaf completer -> root RMW (8 RMWs/round on root)
//             poll root >= 8*(n+1) with s_sleep(1)   (quiet regime)
//   [all] syncthreads (release)
__global__ __launch_bounds__(1024) void admm_r6(
    const float* __restrict__ A, const float* __restrict__ bvec,
    const float* __restrict__ cvec, float* __restrict__ out,
    float* __restrict__ x0, float* __restrict__ x1,
    float* __restrict__ rt, unsigned* __restrict__ bstate)
{
    cg::grid_group grid = cg::this_grid();
    const int tid  = threadIdx.x;
    const int blk  = blockIdx.x;
    const int lane = tid & 63;
    const int wave = tid >> 6;
    const int cgp  = wave >> 2;   // col-group: cols [1024*cgp, +1024)
    const int rq   = wave & 3;    // row-quad : rows 16*blk + 4*rq .. +4

    __shared__ float  abuf[4 * N_COLS];  // 64 KB staging (A rows / rt)
    __shared__ float4 xs4[1024];         // 16 KB staged x (and Ax-phase x)
    __shared__ float  red[4][16];        // per-colgroup row partials
    __shared__ float4 gred[64];          // w-phase reduce scratch
    __shared__ float  wl[16], cw[16];
    __shared__ float  sv[8], uv[8], tpart[16];

    float* xs = reinterpret_cast<float*>(xs4);
    const float4* A4 = reinterpret_cast<const float4*>(A);
    float4* abuf4 = reinterpret_cast<float4*>(abuf);

    // ---- init ----
    if (tid < 16) {
        cw[tid] = cvec[blk * 16 + tid];
        astore(&x0[blk * 16 + tid], 0.0f);
    }
    if (tid < 8) {
        sv[tid] = 0.0f; uv[tid] = 0.0f;
        astore(&rt[blk * 8 + tid], bvec[blk * 8 + tid]);
    }
    if (blk == 0 && tid < 320) bstate[tid] = 0u;

    // ---- precompute register-resident M fragment ----
    float accM[4][16];
    #pragma unroll
    for (int r = 0; r < 4; ++r)
        #pragma unroll
        for (int k = 0; k < 16; ++k) accM[r][k] = 0.0f;

    for (int i0 = 0; i0 < M_ROWS; i0 += 4) {
        #pragma unroll
        for (int ii = 0; ii < 4; ++ii)
            abuf4[ii * 1024 + tid] = A4[(size_t)(i0 + ii) * 1024 + tid];
        __syncthreads();
        #pragma unroll
        for (int ii = 0; ii < 4; ++ii) {
            const float*  row  = abuf + ii * N_COLS;
            const float4* row4 = abuf4 + ii * 1024;
            float4 av[4];
            #pragma unroll
            for (int q = 0; q < 4; ++q)
                av[q] = row4[256 * cgp + 64 * q + lane];
            float cb[4];
            #pragma unroll
            for (int r = 0; r < 4; ++r) cb[r] = row[blk * 16 + rq * 4 + r];
            #pragma unroll
            for (int r = 0; r < 4; ++r)
                #pragma unroll
                for (int q = 0; q < 4; ++q) {
                    accM[r][4 * q + 0] = fmaf(cb[r], av[q].x, accM[r][4 * q + 0]);
                    accM[r][4 * q + 1] = fmaf(cb[r], av[q].y, accM[r][4 * q + 1]);
                    accM[r][4 * q + 2] = fmaf(cb[r], av[q].z, accM[r][4 * q + 2]);
                    accM[r][4 * q + 3] = fmaf(cb[r], av[q].w, accM[r][4 * q + 3]);
                }
        }
        __syncthreads();
    }

    grid.sync();   // single cg sync: publishes x0/rt/bstate
    unsigned bar_n = 0;

    for (int outer = 0; outer < MAX_ITERS_C; ++outer) {
        // ---- w-phase (block-local result): wl = (A^T rt)[16b..16b+16) ----
        abuf[tid]        = aload(&rt[tid]);
        abuf[tid + 1024] = aload(&rt[tid + 1024]);
        __syncthreads();
        {
            const int p = tid >> 2, gq = tid & 3;
            float4 acc = {0.f, 0.f, 0.f, 0.f};
            #pragma unroll
            for (int k2 = 0; k2 < 8; ++k2) {
                const int i = p + 256 * k2;
                const float tv = abuf[i];
                float4 a = A4[(size_t)i * 1024 + blk * 4 + gq];
                acc.x = fmaf(a.x, tv, acc.x); acc.y = fmaf(a.y, tv, acc.y);
                acc.z = fmaf(a.z, tv, acc.z); acc.w = fmaf(a.w, tv, acc.w);
            }
            #pragma unroll
            for (int off = 4; off < 64; off <<= 1) {
                acc.x += __shfl_xor(acc.x, off);
                acc.y += __shfl_xor(acc.y, off);
                acc.z += __shfl_xor(acc.z, off);
                acc.w += __shfl_xor(acc.w, off);
            }
            if ((lane >> 2) == 0) gred[wave * 4 + gq] = acc;
        }
        __syncthreads();
        if (tid < 4) {
            float4 tot = {0.f, 0.f, 0.f, 0.f};
            #pragma unroll
            for (int w = 0; w < 16; ++w) {
                float4 v = gred[w * 4 + tid];
                tot.x += v.x; tot.y += v.y; tot.z += v.z; tot.w += v.w;
            }
            wl[tid * 4 + 0] = tot.x; wl[tid * 4 + 1] = tot.y;
            wl[tid * 4 + 2] = tot.z; wl[tid * 4 + 3] = tot.w;
        }
        __syncthreads();

        // ---- inner PGD: x <- relu(x - step*(c + rho*(Mx - wl))) ----
        for (int inner = 0; inner < INNER_C; ++inner) {
            const float* xsrc = (inner & 1) ? x1 : x0;
            float*       xdst = (inner & 1) ? x0 : x1;

            // coherent vectorized x-exchange: 16 B per thread, once
            {
                float2 lo = aload2(xsrc + 4 * tid);
                float2 hi = aload2(xsrc + 4 * tid + 2);
                xs4[tid] = make_float4(lo.x, lo.y, hi.x, hi.y);
            }
            __syncthreads();                       // (A) xs4 staged

            float4 xq[4];
            #pragma unroll
            for (int q = 0; q < 4; ++q)
                xq[q] = xs4[256 * cgp + 64 * q + lane];

            float4 pd = {0.f, 0.f, 0.f, 0.f};
            #pragma unroll
            for (int q = 0; q < 4; ++q) {
                pd.x = fmaf(accM[0][4*q+0], xq[q].x, pd.x);
                pd.x = fmaf(accM[0][4*q+1], xq[q].y, pd.x);
                pd.x = fmaf(accM[0][4*q+2], xq[q].z, pd.x);
                pd.x = fmaf(accM[0][4*q+3], xq[q].w, pd.x);
                pd.y = fmaf(accM[1][4*q+0], xq[q].x, pd.y);
                pd.y = fmaf(accM[1][4*q+1], xq[q].y, pd.y);
                pd.y = fmaf(accM[1][4*q+2], xq[q].z, pd.y);
                pd.y = fmaf(accM[1][4*q+3], xq[q].w, pd.y);
                pd.z = fmaf(accM[2][4*q+0], xq[q].x, pd.z);
                pd.z = fmaf(accM[2][4*q+1], xq[q].y, pd.z);
                pd.z = fmaf(accM[2][4*q+2], xq[q].z, pd.z);
                pd.z = fmaf(accM[2][4*q+3], xq[q].w, pd.z);
                pd.w = fmaf(accM[3][4*q+0], xq[q].x, pd.w);
                pd.w = fmaf(accM[3][4*q+1], xq[q].y, pd.w);
                pd.w = fmaf(accM[3][4*q+2], xq[q].z, pd.w);
                pd.w = fmaf(accM[3][4*q+3], xq[q].w, pd.w);
            }

            #pragma unroll
            for (int off = 32; off; off >>= 1) {
                pd.x += __shfl_xor(pd.x, off);
                pd.y += __shfl_xor(pd.y, off);
                pd.z += __shfl_xor(pd.z, off);
                pd.w += __shfl_xor(pd.w, off);
            }
            if (lane == 0) {
                red[cgp][rq * 4 + 0] = pd.x;
                red[cgp][rq * 4 + 1] = pd.y;
                red[cgp][rq * 4 + 2] = pd.z;
                red[cgp][rq * 4 + 3] = pd.w;
            }
            __syncthreads();                       // (B) barrier entry; red ready

            // producers = lanes 0..15 of wave 0 (thread0's wave)
            if (tid < 16) {
                const float y = red[0][tid] + red[1][tid]
                              + red[2][tid] + red[3][tid];
                const float g = cw[tid] + RHO_C * (y - wl[tid]);
                float xn = xs[blk * 16 + tid] - STEP_C * g;
                xn = xn > 0.f ? xn : 0.f;
                astore(&xdst[blk * 16 + tid], xn);
            }
            if (tid == 0) {
                asm volatile("s_waitcnt vmcnt(0)" ::: "memory"); // wave-scope drain
                unsigned* leaf = bstate + ((blk & 7) << 5);      // 128-B spread
                unsigned* root = bstate + 256;
                unsigned old = __hip_atomic_fetch_add(
                    leaf, 1u, __ATOMIC_RELAXED, __HIP_MEMORY_SCOPE_AGENT);
                if (old == bar_n * 32u + 31u)
                    __hip_atomic_fetch_add(root, 1u, __ATOMIC_RELAXED,
                                           __HIP_MEMORY_SCOPE_AGENT);
                while (aldu(root) < bar_n * 8u + 8u)
                    __builtin_amdgcn_s_sleep(1);
                asm volatile("" ::: "memory");
            }
            ++bar_n;
            __syncthreads();                       // (C) release
        }
        // INNER_C even -> final x is in x0

        // ---- Ax on own 8 rows + s,u,rt update (block-local) ----
        {
            float2 lo = aload2(x0 + 4 * tid);
            float2 hi = aload2(x0 + 4 * tid + 2);
            xs4[tid] = make_float4(lo.x, lo.y, hi.x, hi.y);
        }
        __syncthreads();
        {
            const int r = blk * 8 + (wave >> 1), h = wave & 1;
            const float4* Ar = A4 + (size_t)r * 1024 + h * 512;
            const float4* xh = xs4 + h * 512;
            float4 acc = {0.f, 0.f, 0.f, 0.f};
            #pragma unroll
            for (int it = 0; it < 8; ++it) {
                float4 a = Ar[it * 64 + lane], xv = xh[it * 64 + lane];
                acc.x = fmaf(a.x, xv.x, acc.x); acc.y = fmaf(a.y, xv.y, acc.y);
                acc.z = fmaf(a.z, xv.z, acc.z); acc.w = fmaf(a.w, xv.w, acc.w);
            }
            float d = acc.x + acc.y + acc.z + acc.w;
            #pragma unroll
            for (int off = 32; off; off >>= 1) d += __shfl_xor(d, off);
            if (lane == 0) tpart[wave] = d;
        }
        __syncthreads();                           // barrier entry; tpart ready
        if (tid < 8) {
            const int i = blk * 8 + tid;
            const float a  = tpart[2 * tid] + tpart[2 * tid + 1];
            const float bb = bvec[i];
            const float uu = uv[tid];
            float sn = a - bb + uu; sn = sn > 0.f ? sn : 0.f;
            const float un = uu + a - sn - bb;
            sv[tid] = sn; uv[tid] = un;
            astore(&rt[i], sn + bb - un);
        }
        if (tid == 0) {
            asm volatile("s_waitcnt vmcnt(0)" ::: "memory");
            unsigned* leaf = bstate + ((blk & 7) << 5);
            unsigned* root = bstate + 256;
            unsigned old = __hip_atomic_fetch_add(
                leaf, 1u, __ATOMIC_RELAXED, __HIP_MEMORY_SCOPE_AGENT);
            if (old == bar_n * 32u + 31u)
                __hip_atomic_fetch_add(root, 1u, __ATOMIC_RELAXED,
                                       __HIP_MEMORY_SCOPE_AGENT);
            while (aldu(root) < bar_n * 8u + 8u)
                __builtin_amdgcn_s_sleep(1);
            asm volatile("" ::: "memory");
        }
        ++bar_n;
        __syncthreads();                           // release
    }

    // ---- outputs: [x(4096), s(2048), u(2048), -u(2048)] ----
    if (tid < 16) out[blk * 16 + tid] = aload(&x0[blk * 16 + tid]);
    if (tid < 8) {
        const int i = blk * 8 + tid;
        out[4096 + i] = sv[tid];
        out[6144 + i] = uv[tid];
        out[8192 + i] = -uv[tid];
    }
}

extern "C" void kernel_launch(void* const* d_in, const int* in_sizes, int n_in,
                              void* d_out, int out_size, void* d_ws, size_t ws_size,
                              hipStream_t stream) {
    const float* A    = (const float*)d_in[0];   // 2048*4096
    const float* bvec = (const float*)d_in[1];   // 2048
    const float* cvec = (const float*)d_in[2];   // 4096
    float* out = (float*)d_out;

    float* ws = (float*)d_ws;
    float* x0 = ws;                    // 4096
    float* x1 = ws + 4096;             // 4096
    float* rt = ws + 8192;             // 2048
    unsigned* bstate = (unsigned*)(ws + 12288);  // 320 uints

    void* args[] = { (void*)&A, (void*)&bvec, (void*)&cvec, (void*)&out,
                     (void*)&x0, (void*)&x1, (void*)&rt, (void*)&bstate };
    hipError_t err = hipLaunchCooperativeKernel((const void*)admm_r6,
                               dim3(256), dim3(1024), args, 0, stream);
    (void)err;
}

// Round 7
// 10806.853 us; speedup vs baseline: 1.5378x; 1.1103x over previous
//
#include <hip/hip_runtime.h>
#include <hip/hip_cooperative_groups.h>

namespace cg = cooperative_groups;

#define M_ROWS 2048
#define N_COLS 4096
#define RHO_C 1.0f
#define STEP_C 5e-05f
#define MAX_ITERS_C 100
#define INNER_C 20

// Relaxed agent-scope atomics: coherent at the Infinity Cache (sc1 path),
// bypassing per-XCD L2 / per-CU L1 — no cache-op fences needed.
// Session law (R1-R6, 6 bracketing experiments): arrival RMWs spread over
// >=8 lines; the POLLED line receives exactly ONE write per round; data
// exchange is read-once agent-scope; pollers back off with s_sleep.
// Every deviation from this structure measured 0.5-2.7 us/round slower.
__device__ __forceinline__ float aload(const float* p) {
    return __hip_atomic_load(p, __ATOMIC_RELAXED, __HIP_MEMORY_SCOPE_AGENT);
}
__device__ __forceinline__ void astore(float* p, float v) {
    __hip_atomic_store(p, v, __ATOMIC_RELAXED, __HIP_MEMORY_SCOPE_AGENT);
}
__device__ __forceinline__ float2 aload2(const float* p) {
    unsigned long long v = __hip_atomic_load(
        (const unsigned long long*)p, __ATOMIC_RELAXED,
        __HIP_MEMORY_SCOPE_AGENT);
    union { unsigned long long u; float2 f; } c; c.u = v; return c.f;
}

// Fence-light 2-level grid barrier. Monotonic counters, no resets.
// Leaves: bs[g*32], g<8 (128 B apart). Root: bs[256]. Epoch: bs[288].
// Pollers watch the EPOCH line only (1 RMW/round on it — quiet regime).
__device__ inline void fast_barrier(unsigned* bs, int blk, unsigned n) {
    __syncthreads();   // each wave drains its own vmcnt before s_barrier
    if (threadIdx.x == 0) {
        __builtin_amdgcn_fence(__ATOMIC_RELEASE, "workgroup");
        unsigned* leaf = bs + ((blk & 7) << 5);
        unsigned* root = bs + 256;
        unsigned* ep   = bs + 288;
        unsigned old = __hip_atomic_fetch_add(leaf, 1u, __ATOMIC_RELAXED,
                                              __HIP_MEMORY_SCOPE_AGENT);
        if (old == n * 32u + 31u) {
            unsigned ro = __hip_atomic_fetch_add(root, 1u, __ATOMIC_RELAXED,
                                                 __HIP_MEMORY_SCOPE_AGENT);
            if (ro == n * 8u + 7u)
                __hip_atomic_fetch_add(ep, 1u, __ATOMIC_RELAXED,
                                       __HIP_MEMORY_SCOPE_AGENT);
        }
        while (__hip_atomic_load(ep, __ATOMIC_RELAXED,
                                 __HIP_MEMORY_SCOPE_AGENT) <= n)
            __builtin_amdgcn_s_sleep(1);
        __builtin_amdgcn_fence(__ATOMIC_ACQUIRE, "workgroup");
    }
    __syncthreads();
}

// 256 blocks (1/CU) x 1024 threads (16 waves), persistent cooperative kernel.
// Gram form: g = c + rho*(M x - A^T rt), M = A^T A held ENTIRELY in registers:
// wave w = (cgp=w>>2, rq=w&3); thread (cgp,rq,lane):
//   accM[r][4q+e] = M[16*blk + 4*rq + r][1024*cgp + 256*q + 4*lane + e]
// so each thread's 16 x-operands are 4 contiguous float4s in a 4096-float xs.
// Block b also owns rows [8b,8b+8) of A (Ax/s,u,rt) and x entries [16b,16b+16).
__global__ __launch_bounds__(1024) void admm_gram(
    const float* __restrict__ A, const float* __restrict__ bvec,
    const float* __restrict__ cvec, float* __restrict__ out,
    float* __restrict__ x0, float* __restrict__ x1,
    float* __restrict__ rt, unsigned* __restrict__ bstate)
{
    cg::grid_group grid = cg::this_grid();
    const int tid  = threadIdx.x;
    const int blk  = blockIdx.x;
    const int lane = tid & 63;
    const int wave = tid >> 6;
    const int cgp  = wave >> 2;   // col-group: cols [1024*cgp, +1024)
    const int rq   = wave & 3;    // row-quad : rows 16*blk + 4*rq .. +4

    __shared__ float  abuf[4 * N_COLS];  // 64 KB staging (A rows / rt)
    __shared__ float4 xs4[1024];         // 16 KB staged x (and Ax-phase x)
    __shared__ float  red[4][16];        // per-colgroup row partials
    __shared__ float4 gred[64];          // w-phase reduce scratch
    __shared__ float  wl[16], cw[16];
    __shared__ float  sv[8], uv[8], tpart[16];

    float* xs = reinterpret_cast<float*>(xs4);
    const float4* A4 = reinterpret_cast<const float4*>(A);
    float4* abuf4 = reinterpret_cast<float4*>(abuf);

    // ---- init ----
    if (tid < 16) {
        cw[tid] = cvec[blk * 16 + tid];
        astore(&x0[blk * 16 + tid], 0.0f);
    }
    if (tid < 8) {
        sv[tid] = 0.0f; uv[tid] = 0.0f;
        astore(&rt[blk * 8 + tid], bvec[blk * 8 + tid]);
    }
    if (blk == 0 && tid < 320) bstate[tid] = 0u;

    // ---- precompute register-resident M fragment ----
    float accM[4][16];
    #pragma unroll
    for (int r = 0; r < 4; ++r)
        #pragma unroll
        for (int k = 0; k < 16; ++k) accM[r][k] = 0.0f;

    for (int i0 = 0; i0 < M_ROWS; i0 += 4) {
        #pragma unroll
        for (int ii = 0; ii < 4; ++ii)
            abuf4[ii * 1024 + tid] = A4[(size_t)(i0 + ii) * 1024 + tid];
        __syncthreads();
        #pragma unroll
        for (int ii = 0; ii < 4; ++ii) {
            const float*  row  = abuf + ii * N_COLS;
            const float4* row4 = abuf4 + ii * 1024;
            float4 av[4];
            #pragma unroll
            for (int q = 0; q < 4; ++q)
                av[q] = row4[256 * cgp + 64 * q + lane];
            float cb[4];
            #pragma unroll
            for (int r = 0; r < 4; ++r) cb[r] = row[blk * 16 + rq * 4 + r];
            #pragma unroll
            for (int r = 0; r < 4; ++r)
                #pragma unroll
                for (int q = 0; q < 4; ++q) {
                    accM[r][4 * q + 0] = fmaf(cb[r], av[q].x, accM[r][4 * q + 0]);
                    accM[r][4 * q + 1] = fmaf(cb[r], av[q].y, accM[r][4 * q + 1]);
                    accM[r][4 * q + 2] = fmaf(cb[r], av[q].z, accM[r][4 * q + 2]);
                    accM[r][4 * q + 3] = fmaf(cb[r], av[q].w, accM[r][4 * q + 3]);
                }
        }
        __syncthreads();
    }

    grid.sync();   // single cg sync: publishes x0/rt/bstate
    unsigned bar_n = 0;

    for (int outer = 0; outer < MAX_ITERS_C; ++outer) {
        // ---- w-phase (block-local result): wl = (A^T rt)[16b..16b+16) ----
        abuf[tid]        = aload(&rt[tid]);
        abuf[tid + 1024] = aload(&rt[tid + 1024]);
        __syncthreads();
        {
            const int p = tid >> 2, gq = tid & 3;
            float4 acc = {0.f, 0.f, 0.f, 0.f};
            #pragma unroll
            for (int k2 = 0; k2 < 8; ++k2) {
                const int i = p + 256 * k2;
                const float tv = abuf[i];
                float4 a = A4[(size_t)i * 1024 + blk * 4 + gq];
                acc.x = fmaf(a.x, tv, acc.x); acc.y = fmaf(a.y, tv, acc.y);
                acc.z = fmaf(a.z, tv, acc.z); acc.w = fmaf(a.w, tv, acc.w);
            }
            #pragma unroll
            for (int off = 4; off < 64; off <<= 1) {
                acc.x += __shfl_xor(acc.x, off);
                acc.y += __shfl_xor(acc.y, off);
                acc.z += __shfl_xor(acc.z, off);
                acc.w += __shfl_xor(acc.w, off);
            }
            if ((lane >> 2) == 0) gred[wave * 4 + gq] = acc;
        }
        __syncthreads();
        if (tid < 4) {
            float4 tot = {0.f, 0.f, 0.f, 0.f};
            #pragma unroll
            for (int w = 0; w < 16; ++w) {
                float4 v = gred[w * 4 + tid];
                tot.x += v.x; tot.y += v.y; tot.z += v.z; tot.w += v.w;
            }
            wl[tid * 4 + 0] = tot.x; wl[tid * 4 + 1] = tot.y;
            wl[tid * 4 + 2] = tot.z; wl[tid * 4 + 3] = tot.w;
        }
        __syncthreads();

        // ---- inner PGD: x <- relu(x - step*(c + rho*(Mx - wl))) ----
        for (int inner = 0; inner < INNER_C; ++inner) {
            const float* xsrc = (inner & 1) ? x1 : x0;
            float*       xdst = (inner & 1) ? x0 : x1;

            // coherent vectorized x-exchange: 16 B per thread, once
            {
                float2 lo = aload2(xsrc + 4 * tid);
                float2 hi = aload2(xsrc + 4 * tid + 2);
                xs4[tid] = make_float4(lo.x, lo.y, hi.x, hi.y);
            }
            __syncthreads();

            float4 xq[4];
            #pragma unroll
            for (int q = 0; q < 4; ++q)
                xq[q] = xs4[256 * cgp + 64 * q + lane];

            float4 pd = {0.f, 0.f, 0.f, 0.f};
            #pragma unroll
            for (int q = 0; q < 4; ++q) {
                pd.x = fmaf(accM[0][4*q+0], xq[q].x, pd.x);
                pd.x = fmaf(accM[0][4*q+1], xq[q].y, pd.x);
                pd.x = fmaf(accM[0][4*q+2], xq[q].z, pd.x);
                pd.x = fmaf(accM[0][4*q+3], xq[q].w, pd.x);
                pd.y = fmaf(accM[1][4*q+0], xq[q].x, pd.y);
                pd.y = fmaf(accM[1][4*q+1], xq[q].y, pd.y);
                pd.y = fmaf(accM[1][4*q+2], xq[q].z, pd.y);
                pd.y = fmaf(accM[1][4*q+3], xq[q].w, pd.y);
                pd.z = fmaf(accM[2][4*q+0], xq[q].x, pd.z);
                pd.z = fmaf(accM[2][4*q+1], xq[q].y, pd.z);
                pd.z = fmaf(accM[2][4*q+2], xq[q].z, pd.z);
                pd.z = fmaf(accM[2][4*q+3], xq[q].w, pd.z);
                pd.w = fmaf(accM[3][4*q+0], xq[q].x, pd.w);
                pd.w = fmaf(accM[3][4*q+1], xq[q].y, pd.w);
                pd.w = fmaf(accM[3][4*q+2], xq[q].z, pd.w);
                pd.w = fmaf(accM[3][4*q+3], xq[q].w, pd.w);
            }

            #pragma unroll
            for (int off = 32; off; off >>= 1) {
                pd.x += __shfl_xor(pd.x, off);
                pd.y += __shfl_xor(pd.y, off);
                pd.z += __shfl_xor(pd.z, off);
                pd.w += __shfl_xor(pd.w, off);
            }
            if (lane == 0) {
                red[cgp][rq * 4 + 0] = pd.x;
                red[cgp][rq * 4 + 1] = pd.y;
                red[cgp][rq * 4 + 2] = pd.z;
                red[cgp][rq * 4 + 3] = pd.w;
            }
            __syncthreads();

            if (tid < 16) {
                const float y = red[0][tid] + red[1][tid]
                              + red[2][tid] + red[3][tid];
                const float g = cw[tid] + RHO_C * (y - wl[tid]);
                float xn = xs[blk * 16 + tid] - STEP_C * g;
                xn = xn > 0.f ? xn : 0.f;
                astore(&xdst[blk * 16 + tid], xn);
            }
            fast_barrier(bstate, blk, bar_n); ++bar_n;
        }
        // INNER_C even -> final x is in x0

        // ---- Ax on own 8 rows + s,u,rt update (block-local) ----
        {
            float2 lo = aload2(x0 + 4 * tid);
            float2 hi = aload2(x0 + 4 * tid + 2);
            xs4[tid] = make_float4(lo.x, lo.y, hi.x, hi.y);
        }
        __syncthreads();
        {
            const int r = blk * 8 + (wave >> 1), h = wave & 1;
            const float4* Ar = A4 + (size_t)r * 1024 + h * 512;
            const float4* xh = xs4 + h * 512;
            float4 acc = {0.f, 0.f, 0.f, 0.f};
            #pragma unroll
            for (int it = 0; it < 8; ++it) {
                float4 a = Ar[it * 64 + lane], xv = xh[it * 64 + lane];
                acc.x = fmaf(a.x, xv.x, acc.x); acc.y = fmaf(a.y, xv.y, acc.y);
                acc.z = fmaf(a.z, xv.z, acc.z); acc.w = fmaf(a.w, xv.w, acc.w);
            }
            float d = acc.x + acc.y + acc.z + acc.w;
            #pragma unroll
            for (int off = 32; off; off >>= 1) d += __shfl_xor(d, off);
            if (lane == 0) tpart[wave] = d;
        }
        __syncthreads();
        if (tid < 8) {
            const int i = blk * 8 + tid;
            const float a  = tpart[2 * tid] + tpart[2 * tid + 1];
            const float bb = bvec[i];
            const float uu = uv[tid];
            float sn = a - bb + uu; sn = sn > 0.f ? sn : 0.f;
            const float un = uu + a - sn - bb;
            sv[tid] = sn; uv[tid] = un;
            astore(&rt[i], sn + bb - un);
        }
        fast_barrier(bstate, blk, bar_n); ++bar_n;
    }

    // ---- outputs: [x(4096), s(2048), u(2048), -u(2048)] ----
    if (tid < 16) out[blk * 16 + tid] = aload(&x0[blk * 16 + tid]);
    if (tid < 8) {
        const int i = blk * 8 + tid;
        out[4096 + i] = sv[tid];
        out[6144 + i] = uv[tid];
        out[8192 + i] = -uv[tid];
    }
}

extern "C" void kernel_launch(void* const* d_in, const int* in_sizes, int n_in,
                              void* d_out, int out_size, void* d_ws, size_t ws_size,
                              hipStream_t stream) {
    const float* A    = (const float*)d_in[0];   // 2048*4096
    const float* bvec = (const float*)d_in[1];   // 2048
    const float* cvec = (const float*)d_in[2];   // 4096
    float* out = (float*)d_out;

    float* ws = (float*)d_ws;
    float* x0 = ws;                    // 4096
    float* x1 = ws + 4096;             // 4096
    float* rt = ws + 8192;             // 2048
    unsigned* bstate = (unsigned*)(ws + 12288);  // 320 uints

    void* args[] = { (void*)&A, (void*)&bvec, (void*)&cvec, (void*)&out,
                     (void*)&x0, (void*)&x1, (void*)&rt, (void*)&bstate };
    hipError_t err = hipLaunchCooperativeKernel((const void*)admm_gram,
                               dim3(256), dim3(1024), args, 0, stream);
    (void)err;
}